// Round 8
// baseline (347.140 us; speedup 1.0000x reference)
//
#include <hip/hip_runtime.h>

#define DIMD 256
#define PDIM 256
#define NB   8
#define LSEQ 4096
#define MTOT (NB*LSEQ)      // 32768
#define FDIM 2560
#define NCHUNK 64
#define CLEN 64

typedef __attribute__((ext_vector_type(8))) short s8bf;   // 8 bf16 = 4 VGPRs
typedef __attribute__((ext_vector_type(4))) float f32x4;

#define MFMA16(a,b,c) __builtin_amdgcn_mfma_f32_16x16x32_bf16((a),(b),(c),0,0,0)

// ---- workspace layout (float offsets) ----
static const size_t OFF_LBR  = 0;      // lam_bar re           [256]
static const size_t OFF_LBI  = 256;    // lam_bar im
static const size_t OFF_A64R = 512;    // lam_bar^64 re
static const size_t OFF_A64I = 768;
static const size_t OFF_WR   = 1024;   // w = B_bar . l1_w
static const size_t OFF_WI   = 1280;
static const size_t OFF_CR   = 1536;   // c = B_bar . l1_b
static const size_t OFF_CI   = 1792;
static const size_t OFF_E_RE   = 4096;                       // chunk end states [8][64][256]
static const size_t OFF_E_IM   = OFF_E_RE   + 131072;
static const size_t OFF_CAR_RE = OFF_E_IM   + 131072;        // chunk carry-in   [8][64][256]
static const size_t OFF_CAR_IM = OFF_CAR_RE + 131072;
static const size_t OFF_H1     = OFF_CAR_IM + 131072;        // h1 bf16 [32768][256] (4,194,304 floats)
static const size_t OFF_ENC16  = OFF_H1     + 4194304;       // enc_w bf16 [2560][256]
static const size_t OFF_DEC16  = OFF_ENC16  + 327680;        // dec_w bf16 [256][2560]
static const size_t OFF_CC16   = OFF_DEC16  + 327680;        // Cc bf16 [256][512] k-interleaved
// end ~ 5.4M floats = 21.6 MB

__device__ __forceinline__ ushort f2bf(float f) {
    union { float f; unsigned u; } v; v.f = f;
    unsigned u = v.u;
    return (ushort)((u + 0x7FFFu + ((u >> 16) & 1u)) >> 16);   // RNE
}
__device__ __forceinline__ float bf2f(ushort h) {
    union { unsigned u; float f; } v; v.u = ((unsigned)h) << 16;
    return v.f;
}
// tanh = 1 - 2/(e^{2x}+1); rcp(inf)=0 -> +1, e^{2x}->0 -> -1: no clamps needed
__device__ __forceinline__ float fast_tanh(float x) {
    float e = __expf(2.f * x);
    return 1.f - 2.f * __builtin_amdgcn_rcpf(e + 1.f);
}
// fs-row swizzle: spreads both read groups (m=lr consecutive) and write groups (m=4*lg+r)
__device__ __forceinline__ int fsw(int m) { return ((m ^ (m >> 2)) & 7) << 4; }

// ---- per-p constants: lam_bar, lam_bar^64, w, c ----
__global__ void k_consts(const float* __restrict__ l1w, const float* __restrict__ l1b,
                         const float* __restrict__ lam_re, const float* __restrict__ lam_im,
                         const float* __restrict__ B_re, const float* __restrict__ B_im,
                         const float* __restrict__ log_step, float* __restrict__ ws) {
    int p = threadIdx.x;
    float st = expf(log_step[p]);
    float lr = lam_re[p], li = lam_im[p];
    float zr = lr * st, zi = li * st;
    float er = expf(zr);
    float lbr = er * cosf(zi), lbi = er * sinf(zi);
    float den = lr * lr + li * li;
    float nr = lbr - 1.0f, ni = lbi;
    float facr = (nr * lr + ni * li) / den;
    float faci = (ni * lr - nr * li) / den;
    float dwr = 0.f, dwi = 0.f, dbr = 0.f, dbi = 0.f;
    for (int h = 0; h < DIMD; ++h) {
        float br = B_re[p * DIMD + h], bi = B_im[p * DIMD + h];
        float w1 = l1w[h], b1 = l1b[h];
        dwr = fmaf(br, w1, dwr); dwi = fmaf(bi, w1, dwi);
        dbr = fmaf(br, b1, dbr); dbi = fmaf(bi, b1, dbi);
    }
    float wr = facr * dwr - faci * dwi, wi = facr * dwi + faci * dwr;
    float cr = facr * dbr - faci * dbi, ci = facr * dbi + faci * dbr;
    float ar = lbr, ai = lbi;
    for (int s = 0; s < 6; ++s) { float t = ar * ar - ai * ai; ai = 2.f * ar * ai; ar = t; }
    ws[OFF_LBR + p] = lbr;  ws[OFF_LBI + p] = lbi;
    ws[OFF_A64R + p] = ar;  ws[OFF_A64I + p] = ai;
    ws[OFF_WR + p] = wr;    ws[OFF_WI + p] = wi;
    ws[OFF_CR + p] = cr;    ws[OFF_CI + p] = ci;
}

// ---- weight prep: enc/dec -> bf16 ; Cc16 k-INTERLEAVED to match xs layout ----
__global__ void k_prep(const float* __restrict__ enc_w, const float* __restrict__ dec_w,
                       const float* __restrict__ C_re, const float* __restrict__ C_im,
                       ushort* __restrict__ enc16, ushort* __restrict__ dec16,
                       ushort* __restrict__ cc16) {
    int bid = blockIdx.x, t = threadIdx.x;
    if (bid < 2560) {
        int i = bid * 256 + t;
        enc16[i] = f2bf(enc_w[i]);
        dec16[i] = f2bf(dec_w[i]);
    } else {
        int j = (bid - 2560) * 256 + t;       // 512 blocks -> 131072 = 256*512
        int h = j >> 9, c = j & 511;
        int p = c >> 1;
        float v = ((c & 1) == 0) ? 2.f * C_re[h * 256 + p] : -2.f * C_im[h * 256 + p];
        cc16[j] = f2bf(v);
    }
}

// ---- scan pass A: per (b,chunk,p) chunk-local end state (zero init) ----
__global__ void k_scanA(const float* __restrict__ x, float* __restrict__ ws) {
    int p = threadIdx.x, chunk = blockIdx.x, b = blockIdx.y;
    float lbr = ws[OFF_LBR + p], lbi = ws[OFF_LBI + p];
    float wr = ws[OFF_WR + p], wi = ws[OFF_WI + p];
    float cr = ws[OFF_CR + p], ci = ws[OFF_CI + p];
    const float* xb = x + (size_t)b * LSEQ + chunk * CLEN;
    float sr = 0.f, si = 0.f;
    for (int t = 0; t < CLEN; ++t) {
        float xv = xb[t];
        float bur = fmaf(xv, wr, cr), bui = fmaf(xv, wi, ci);
        float nsr = fmaf(lbr, sr, fmaf(-lbi, si, bur));
        float nsi = fmaf(lbr, si, fmaf(lbi, sr, bui));
        sr = nsr; si = nsi;
    }
    size_t idx = ((size_t)b * NCHUNK + chunk) * PDIM + p;
    ws[OFF_E_RE + idx] = sr; ws[OFF_E_IM + idx] = si;
}

// ---- scan pass B: combine chunks, store carry-in per chunk ----
__global__ void k_scanB(float* __restrict__ ws) {
    int p = threadIdx.x, b = blockIdx.x;
    float ar = ws[OFF_A64R + p], ai = ws[OFF_A64I + p];
    float sr = 0.f, si = 0.f;
    for (int c = 0; c < NCHUNK; ++c) {
        size_t idx = ((size_t)b * NCHUNK + c) * PDIM + p;
        ws[OFF_CAR_RE + idx] = sr; ws[OFF_CAR_IM + idx] = si;
        float er = ws[OFF_E_RE + idx], ei = ws[OFF_E_IM + idx];
        float nsr = fmaf(ar, sr, fmaf(-ai, si, er));
        float nsi = fmaf(ar, si, fmaf(ai, sr, ei));
        sr = nsr; si = nsi;
    }
}

// ---- fused scanC + C-projection (bf16 MFMA) + S5 epilogue -> h1 bf16 ----
__global__ __launch_bounds__(256) void k_scg(
        const float* __restrict__ x, const float* __restrict__ ws,
        const ushort* __restrict__ cc16, const float* __restrict__ l1w,
        const float* __restrict__ l1b, const float* __restrict__ Dv,
        ushort* __restrict__ h1) {
    __shared__ ushort xs[64 * 512];   // 64 KB: row=t (1024B), col 2p=re, 2p+1=im
    __shared__ float xbuf[64];
    const int t = threadIdx.x;
    const int chunk = blockIdx.x, b = blockIdx.y;
    const size_t row0 = (size_t)b * LSEQ + chunk * CLEN;
    if (t < 64) xbuf[t] = x[row0 + t];
    const int p = t;
    float lbr = ws[OFF_LBR + p], lbi = ws[OFF_LBI + p];
    float wr = ws[OFF_WR + p], wi = ws[OFF_WI + p];
    float cr = ws[OFF_CR + p], ci = ws[OFF_CI + p];
    size_t cidx = ((size_t)b * NCHUNK + chunk) * PDIM + p;
    float sr = ws[OFF_CAR_RE + cidx], si = ws[OFF_CAR_IM + cidx];
    __syncthreads();
    for (int tt = 0; tt < CLEN; ++tt) {
        float xv = xbuf[tt];
        float bur = fmaf(xv, wr, cr), bui = fmaf(xv, wi, ci);
        float nsr = fmaf(lbr, sr, fmaf(-lbi, si, bur));
        float nsi = fmaf(lbr, si, fmaf(lbi, sr, bui));
        sr = nsr; si = nsi;
        unsigned pk;
        asm("v_cvt_pk_bf16_f32 %0, %1, %2" : "=v"(pk) : "v"(sr), "v"(si));
        *(unsigned*)((char*)xs + tt * 1024 + ((p * 4) ^ ((tt & 7) << 4))) = pk;
    }
    __syncthreads();
    // GEMM: out 64x256, K=512
    const int w = t >> 6, l = t & 63, lr = l & 15, lg = l >> 4;
    const f32x4 fz = {0.f, 0.f, 0.f, 0.f};
    f32x4 acc[4][4];
    #pragma unroll
    for (int mi = 0; mi < 4; ++mi)
        #pragma unroll
        for (int nj = 0; nj < 4; ++nj) acc[mi][nj] = fz;
    for (int ks = 0; ks < 16; ++ks) {
        s8bf a[4];
        #pragma unroll
        for (int mi = 0; mi < 4; ++mi) {
            int row = mi * 16 + lr;
            a[mi] = *(const s8bf*)((const char*)xs + row * 1024 + ((ks * 64 + lg * 16) ^ ((row & 7) << 4)));
        }
        #pragma unroll
        for (int nj = 0; nj < 4; ++nj) {
            int n = w * 64 + nj * 16 + lr;
            s8bf bfrag = *(const s8bf*)(cc16 + (size_t)n * 512 + ks * 32 + lg * 8);
            #pragma unroll
            for (int mi = 0; mi < 4; ++mi)
                acc[mi][nj] = MFMA16(a[mi], bfrag, acc[mi][nj]);
        }
    }
    // epilogue: u = x*l1w + l1b ; h1 = tanh(D*u + 2Re(Cx)) + u   (2x folded into Cc16)
    #pragma unroll
    for (int nj = 0; nj < 4; ++nj) {
        int n = w * 64 + nj * 16 + lr;
        float l1wn = l1w[n], l1bn = l1b[n], dn = Dv[n];
        #pragma unroll
        for (int mi = 0; mi < 4; ++mi)
            #pragma unroll
            for (int r = 0; r < 4; ++r) {
                int mrow = mi * 16 + lg * 4 + r;
                float u = fmaf(xbuf[mrow], l1wn, l1bn);
                float s = fmaf(dn, u, acc[mi][nj][r]);
                h1[(row0 + mrow) * DIMD + n] = f2bf(fast_tanh(s) + u);
            }
    }
}

// ---- fused FFN v3: bf16 MFMA, M=64/block, 8 waves, FDIM chunks of 128 ----
// KEY CHANGE vs v2: phase-1 A-fragments (h1) are loaded ONCE into registers
// (aReg[4][8], 128 VGPR) instead of re-read from LDS every chunk (20x).
// Cuts per-CU LDS read traffic ~6x (was the measured bottleneck: 48 b128
// reads/wave/chunk at ~85 B/cyc ~= 77us). Occupancy drops to 2 waves/SIMD
// (launch_bounds(512,2), VGPR ~215) -- deliberate trade.
__global__ __launch_bounds__(512, 2) void k_ff2(
        const ushort* __restrict__ h1g, const ushort* __restrict__ enc16,
        const float* __restrict__ enc_b, const ushort* __restrict__ dec16,
        const float* __restrict__ dec_b, const float* __restrict__ l2w,
        const float* __restrict__ l2b, float* __restrict__ out) {
    __shared__ ushort h1s[64 * 256];   // 32 KB, XOR-swizzled rows (512 B stride)
    __shared__ ushort fs[64 * 128];    // 16 KB, fsw-swizzled rows (256 B stride)
    __shared__ float osum[64];
    const int t = threadIdx.x;
    const int m0 = blockIdx.x * 64;
    const int w = t >> 6, l = t & 63;
    const int lr = l & 15, lg = l >> 4;

    #pragma unroll
    for (int e = 0; e < 4; ++e) {
        int flat = e * 512 + t;
        int row = flat >> 5, unit = flat & 31;
        s8bf v = *(const s8bf*)(h1g + (size_t)(m0 + row) * 256 + unit * 8);
        *(s8bf*)((char*)h1s + row * 512 + ((unit * 16) ^ ((row & 7) << 4))) = v;
    }
    if (t < 64) osum[t] = 0.f;
    __syncthreads();

    // ---- one-time: fill A-register file from h1s (same swizzled addressing) ----
    s8bf aReg[4][8];
    #pragma unroll
    for (int mi = 0; mi < 4; ++mi) {
        int row = mi * 16 + lr;
        #pragma unroll
        for (int kd = 0; kd < 8; ++kd) {
            int kb = kd * 64 + lg * 16;
            aReg[mi][kd] = *(const s8bf*)((const char*)h1s + row * 512 + (kb ^ ((row & 7) << 4)));
        }
    }

    const f32x4 fz = {0.f, 0.f, 0.f, 0.f};
    f32x4 acc[4][2];
    #pragma unroll
    for (int mi = 0; mi < 4; ++mi) { acc[mi][0] = fz; acc[mi][1] = fz; }

    const ushort* encBase  = enc16 + (size_t)(w * 16 + lr) * 256;
    const ushort* decBase0 = dec16 + (size_t)(w * 32 + lr) * 2560;
    const ushort* decBase1 = dec16 + (size_t)(w * 32 + 16 + lr) * 2560;

    for (int c = 0; c < 20; ++c) {
        const int k0 = c * 128;
        // ---- phase 1: f chunk [64][128]; A from registers, B(enc) from L2 ----
        f32x4 facc[4] = {fz, fz, fz, fz};
        const ushort* encRow = encBase + (size_t)k0 * 256;
        #pragma unroll
        for (int kd = 0; kd < 8; ++kd) {
            s8bf bfrag = *(const s8bf*)(encRow + kd * 32 + lg * 8);
            #pragma unroll
            for (int mi = 0; mi < 4; ++mi)
                facc[mi] = MFMA16(aReg[mi][kd], bfrag, facc[mi]);
        }
        float ebv = enc_b[k0 + w * 16 + lr];
        __syncthreads();                      // prev chunk's phase-2 done reading fs
        #pragma unroll
        for (int mi = 0; mi < 4; ++mi)
            #pragma unroll
            for (int r = 0; r < 4; ++r) {
                int m = mi * 16 + 4 * lg + r;
                int kc = w * 16 + lr;
                *(ushort*)((char*)fs + m * 256 + ((kc * 2) ^ fsw(m))) =
                    f2bf(fast_tanh(facc[mi][r] + ebv));
            }
        __syncthreads();                      // fs chunk ready
        // ---- phase 2: acc += f @ dec^T ; wave w owns h2-cols w*32+{0..31} ----
        #pragma unroll
        for (int kk = 0; kk < 4; ++kk) {
            s8bf b0 = *(const s8bf*)(decBase0 + k0 + kk * 32 + lg * 8);
            s8bf b1 = *(const s8bf*)(decBase1 + k0 + kk * 32 + lg * 8);
            #pragma unroll
            for (int mi = 0; mi < 4; ++mi) {
                int row = mi * 16 + lr;
                int kb = kk * 64 + lg * 16;
                s8bf a = *(const s8bf*)((const char*)fs + row * 256 + (kb ^ fsw(row)));
                acc[mi][0] = MFMA16(a, b0, acc[mi][0]);
                acc[mi][1] = MFMA16(a, b1, acc[mi][1]);
            }
        }
    }
    // ---- epilogue: +dec_b + residual, dot l2w, reduce ----
    const int n0 = w * 32 + lr, n1 = n0 + 16;
    const float db0 = dec_b[n0], db1 = dec_b[n1];
    const float w0 = l2w[n0], w1 = l2w[n1];
    #pragma unroll
    for (int mi = 0; mi < 4; ++mi)
        #pragma unroll
        for (int r = 0; r < 4; ++r) {
            int m = mi * 16 + 4 * lg + r;
            float r0 = bf2f(*(const ushort*)((const char*)h1s + m * 512 + ((2 * n0) ^ ((m & 7) << 4))));
            float r1 = bf2f(*(const ushort*)((const char*)h1s + m * 512 + ((2 * n1) ^ ((m & 7) << 4))));
            float s = (acc[mi][0][r] + db0 + r0) * w0 + (acc[mi][1][r] + db1 + r1) * w1;
            s += __shfl_xor(s, 1, 16);
            s += __shfl_xor(s, 2, 16);
            s += __shfl_xor(s, 4, 16);
            s += __shfl_xor(s, 8, 16);
            if (lr == 0) atomicAdd(&osum[m], s);
        }
    __syncthreads();
    if (t < 64) out[m0 + t] = osum[t] + l2b[0];
}

extern "C" void kernel_launch(void* const* d_in, const int* in_sizes, int n_in,
                              void* d_out, int out_size, void* d_ws, size_t ws_size,
                              hipStream_t stream) {
    const float* x       = (const float*)d_in[0];
    const float* l1w     = (const float*)d_in[1];
    const float* l1b     = (const float*)d_in[2];
    const float* lam_re  = (const float*)d_in[3];
    const float* lam_im  = (const float*)d_in[4];
    const float* B_re    = (const float*)d_in[5];
    const float* B_im    = (const float*)d_in[6];
    const float* C_re    = (const float*)d_in[7];
    const float* C_im    = (const float*)d_in[8];
    const float* Dv      = (const float*)d_in[9];
    const float* log_stp = (const float*)d_in[10];
    const float* enc_w   = (const float*)d_in[11];
    const float* enc_b   = (const float*)d_in[12];
    const float* dec_w   = (const float*)d_in[13];
    const float* dec_b   = (const float*)d_in[14];
    const float* l2w     = (const float*)d_in[15];
    const float* l2b     = (const float*)d_in[16];
    float* ws  = (float*)d_ws;
    float* out = (float*)d_out;
    ushort* h1_16 = (ushort*)(ws + OFF_H1);
    ushort* enc16 = (ushort*)(ws + OFF_ENC16);
    ushort* dec16 = (ushort*)(ws + OFF_DEC16);
    ushort* cc16  = (ushort*)(ws + OFF_CC16);

    hipLaunchKernelGGL(k_consts, dim3(1), dim3(256), 0, stream,
                       l1w, l1b, lam_re, lam_im, B_re, B_im, log_stp, ws);
    hipLaunchKernelGGL(k_prep, dim3(3072), dim3(256), 0, stream,
                       enc_w, dec_w, C_re, C_im, enc16, dec16, cc16);
    hipLaunchKernelGGL(k_scanA, dim3(NCHUNK, NB), dim3(256), 0, stream, x, ws);
    hipLaunchKernelGGL(k_scanB, dim3(NB), dim3(256), 0, stream, ws);
    hipLaunchKernelGGL(k_scg, dim3(NCHUNK, NB), dim3(256), 0, stream,
                       x, ws, cc16, l1w, l1b, Dv, h1_16);
    hipLaunchKernelGGL(k_ff2, dim3(MTOT / 64), dim3(512), 0, stream,
                       h1_16, enc16, enc_b, dec16, dec_b, l2w, l2b, out);
}

// Round 9
// 309.347 us; speedup vs baseline: 1.1222x; 1.1222x over previous
//
#include <hip/hip_runtime.h>

#define DIMD 256
#define PDIM 256
#define NB   8
#define LSEQ 4096
#define MTOT (NB*LSEQ)      // 32768
#define FDIM 2560
#define NCHUNK 64
#define CLEN 64

typedef __attribute__((ext_vector_type(8))) short s8bf;   // 8 bf16 = 4 VGPRs
typedef __attribute__((ext_vector_type(4))) float f32x4;

#define MFMA16(a,b,c) __builtin_amdgcn_mfma_f32_16x16x32_bf16((a),(b),(c),0,0,0)

// ---- workspace layout (float offsets) ----
static const size_t OFF_LBR  = 0;      // lam_bar re           [256]
static const size_t OFF_LBI  = 256;    // lam_bar im
static const size_t OFF_A64R = 512;    // lam_bar^64 re
static const size_t OFF_A64I = 768;
static const size_t OFF_WR   = 1024;   // w = B_bar . l1_w
static const size_t OFF_WI   = 1280;
static const size_t OFF_CR   = 1536;   // c = B_bar . l1_b
static const size_t OFF_CI   = 1792;
static const size_t OFF_E_RE   = 4096;                       // chunk end states [8][64][256]
static const size_t OFF_E_IM   = OFF_E_RE   + 131072;
static const size_t OFF_CAR_RE = OFF_E_IM   + 131072;        // chunk carry-in   [8][64][256]
static const size_t OFF_CAR_IM = OFF_CAR_RE + 131072;
static const size_t OFF_H1     = OFF_CAR_IM + 131072;        // h1 bf16 [32768][256] (4,194,304 floats)
static const size_t OFF_ENC16  = OFF_H1     + 4194304;       // enc_w bf16 [2560][256]
static const size_t OFF_DEC16  = OFF_ENC16  + 327680;        // dec_w bf16 [256][2560]
static const size_t OFF_CC16   = OFF_DEC16  + 327680;        // Cc bf16 [256][512] k-interleaved
// end ~ 5.4M floats = 21.6 MB

__device__ __forceinline__ ushort f2bf(float f) {
    union { float f; unsigned u; } v; v.f = f;
    unsigned u = v.u;
    return (ushort)((u + 0x7FFFu + ((u >> 16) & 1u)) >> 16);   // RNE
}
__device__ __forceinline__ float bf2f(ushort h) {
    union { unsigned u; float f; } v; v.u = ((unsigned)h) << 16;
    return v.f;
}
// tanh = 1 - 2/(e^{2x}+1); rcp(inf)=0 -> +1, e^{2x}->0 -> -1: no clamps needed
__device__ __forceinline__ float fast_tanh(float x) {
    float e = __expf(2.f * x);
    return 1.f - 2.f * __builtin_amdgcn_rcpf(e + 1.f);
}
// fs-row swizzle: spreads both read groups (m=lr consecutive) and write groups (m=4*lg+r)
__device__ __forceinline__ int fsw(int m) { return ((m ^ (m >> 2)) & 7) << 4; }

// ---- weight prep (+ folded-in per-p consts): one launch ----
// bid < 2560: enc/dec -> bf16 ; 2560..3071: Cc16 k-interleaved ; 3072: consts
__global__ void k_prep(const float* __restrict__ enc_w, const float* __restrict__ dec_w,
                       const float* __restrict__ C_re, const float* __restrict__ C_im,
                       const float* __restrict__ l1w, const float* __restrict__ l1b,
                       const float* __restrict__ lam_re, const float* __restrict__ lam_im,
                       const float* __restrict__ B_re, const float* __restrict__ B_im,
                       const float* __restrict__ log_step,
                       ushort* __restrict__ enc16, ushort* __restrict__ dec16,
                       ushort* __restrict__ cc16, float* __restrict__ ws) {
    int bid = blockIdx.x, t = threadIdx.x;
    if (bid < 2560) {
        int i = bid * 256 + t;
        enc16[i] = f2bf(enc_w[i]);
        dec16[i] = f2bf(dec_w[i]);
    } else if (bid < 3072) {
        int j = (bid - 2560) * 256 + t;       // 512 blocks -> 131072 = 256*512
        int h = j >> 9, c = j & 511;
        int p = c >> 1;
        // Cc16[h][2p] = 2*C_re[h][p] ; Cc16[h][2p+1] = -2*C_im[h][p]  (matches xs)
        float v = ((c & 1) == 0) ? 2.f * C_re[h * 256 + p] : -2.f * C_im[h * 256 + p];
        cc16[j] = f2bf(v);
    } else {
        int p = t;
        float st = expf(log_step[p]);
        float lr = lam_re[p], li = lam_im[p];
        float zr = lr * st, zi = li * st;
        float er = expf(zr);
        float lbr = er * cosf(zi), lbi = er * sinf(zi);
        float den = lr * lr + li * li;
        float nr = lbr - 1.0f, ni = lbi;
        float facr = (nr * lr + ni * li) / den;
        float faci = (ni * lr - nr * li) / den;
        float dwr = 0.f, dwi = 0.f, dbr = 0.f, dbi = 0.f;
        for (int h = 0; h < DIMD; ++h) {
            float br = B_re[p * DIMD + h], bi = B_im[p * DIMD + h];
            float w1 = l1w[h], b1 = l1b[h];
            dwr = fmaf(br, w1, dwr); dwi = fmaf(bi, w1, dwi);
            dbr = fmaf(br, b1, dbr); dbi = fmaf(bi, b1, dbi);
        }
        float wr = facr * dwr - faci * dwi, wi = facr * dwi + faci * dwr;
        float cr = facr * dbr - faci * dbi, ci = facr * dbi + faci * dbr;
        float ar = lbr, ai = lbi;
        for (int s = 0; s < 6; ++s) { float tq = ar * ar - ai * ai; ai = 2.f * ar * ai; ar = tq; }
        ws[OFF_LBR + p] = lbr;  ws[OFF_LBI + p] = lbi;
        ws[OFF_A64R + p] = ar;  ws[OFF_A64I + p] = ai;
        ws[OFF_WR + p] = wr;    ws[OFF_WI + p] = wi;
        ws[OFF_CR + p] = cr;    ws[OFF_CI + p] = ci;
    }
}

// ---- scan pass A: per (b,chunk,p) chunk-local end state (zero init) ----
__global__ void k_scanA(const float* __restrict__ x, float* __restrict__ ws) {
    int p = threadIdx.x, chunk = blockIdx.x, b = blockIdx.y;
    float lbr = ws[OFF_LBR + p], lbi = ws[OFF_LBI + p];
    float wr = ws[OFF_WR + p], wi = ws[OFF_WI + p];
    float cr = ws[OFF_CR + p], ci = ws[OFF_CI + p];
    const float* xb = x + (size_t)b * LSEQ + chunk * CLEN;
    float sr = 0.f, si = 0.f;
    for (int t = 0; t < CLEN; ++t) {
        float xv = xb[t];
        float bur = fmaf(xv, wr, cr), bui = fmaf(xv, wi, ci);
        float nsr = fmaf(lbr, sr, fmaf(-lbi, si, bur));
        float nsi = fmaf(lbr, si, fmaf(lbi, sr, bui));
        sr = nsr; si = nsi;
    }
    size_t idx = ((size_t)b * NCHUNK + chunk) * PDIM + p;
    ws[OFF_E_RE + idx] = sr; ws[OFF_E_IM + idx] = si;
}

// ---- scan pass B: combine chunks, store carry-in per chunk ----
__global__ void k_scanB(float* __restrict__ ws) {
    int p = threadIdx.x, b = blockIdx.x;
    float ar = ws[OFF_A64R + p], ai = ws[OFF_A64I + p];
    float sr = 0.f, si = 0.f;
    for (int c = 0; c < NCHUNK; ++c) {
        size_t idx = ((size_t)b * NCHUNK + c) * PDIM + p;
        ws[OFF_CAR_RE + idx] = sr; ws[OFF_CAR_IM + idx] = si;
        float er = ws[OFF_E_RE + idx], ei = ws[OFF_E_IM + idx];
        float nsr = fmaf(ar, sr, fmaf(-ai, si, er));
        float nsi = fmaf(ar, si, fmaf(ai, sr, ei));
        sr = nsr; si = nsi;
    }
}

// ---- fused scanC + C-projection (bf16 MFMA) + S5 epilogue -> h1 bf16 ----
__global__ __launch_bounds__(256) void k_scg(
        const float* __restrict__ x, const float* __restrict__ ws,
        const ushort* __restrict__ cc16, const float* __restrict__ l1w,
        const float* __restrict__ l1b, const float* __restrict__ Dv,
        ushort* __restrict__ h1) {
    __shared__ ushort xs[64 * 512];   // 64 KB: row=t (1024B), col 2p=re, 2p+1=im
    __shared__ float xbuf[64];
    const int t = threadIdx.x;
    const int chunk = blockIdx.x, b = blockIdx.y;
    const size_t row0 = (size_t)b * LSEQ + chunk * CLEN;
    if (t < 64) xbuf[t] = x[row0 + t];
    const int p = t;
    float lbr = ws[OFF_LBR + p], lbi = ws[OFF_LBI + p];
    float wr = ws[OFF_WR + p], wi = ws[OFF_WI + p];
    float cr = ws[OFF_CR + p], ci = ws[OFF_CI + p];
    size_t cidx = ((size_t)b * NCHUNK + chunk) * PDIM + p;
    float sr = ws[OFF_CAR_RE + cidx], si = ws[OFF_CAR_IM + cidx];
    __syncthreads();
    for (int tt = 0; tt < CLEN; ++tt) {
        float xv = xbuf[tt];
        float bur = fmaf(xv, wr, cr), bui = fmaf(xv, wi, ci);
        float nsr = fmaf(lbr, sr, fmaf(-lbi, si, bur));
        float nsi = fmaf(lbr, si, fmaf(lbi, sr, bui));
        sr = nsr; si = nsi;
        unsigned pk;
        asm("v_cvt_pk_bf16_f32 %0, %1, %2" : "=v"(pk) : "v"(sr), "v"(si));
        *(unsigned*)((char*)xs + tt * 1024 + ((p * 4) ^ ((tt & 7) << 4))) = pk;
    }
    __syncthreads();
    // GEMM: out 64x256, K=512
    const int w = t >> 6, l = t & 63, lr = l & 15, lg = l >> 4;
    const f32x4 fz = {0.f, 0.f, 0.f, 0.f};
    f32x4 acc[4][4];
    #pragma unroll
    for (int mi = 0; mi < 4; ++mi)
        #pragma unroll
        for (int nj = 0; nj < 4; ++nj) acc[mi][nj] = fz;
    for (int ks = 0; ks < 16; ++ks) {
        s8bf a[4];
        #pragma unroll
        for (int mi = 0; mi < 4; ++mi) {
            int row = mi * 16 + lr;
            a[mi] = *(const s8bf*)((const char*)xs + row * 1024 + ((ks * 64 + lg * 16) ^ ((row & 7) << 4)));
        }
        #pragma unroll
        for (int nj = 0; nj < 4; ++nj) {
            int n = w * 64 + nj * 16 + lr;
            s8bf bfrag = *(const s8bf*)(cc16 + (size_t)n * 512 + ks * 32 + lg * 8);
            #pragma unroll
            for (int mi = 0; mi < 4; ++mi)
                acc[mi][nj] = MFMA16(a[mi], bfrag, acc[mi][nj]);
        }
    }
    // epilogue: u = x*l1w + l1b ; h1 = tanh(D*u + 2Re(Cx)) + u   (2x folded into Cc16)
    #pragma unroll
    for (int nj = 0; nj < 4; ++nj) {
        int n = w * 64 + nj * 16 + lr;
        float l1wn = l1w[n], l1bn = l1b[n], dn = Dv[n];
        #pragma unroll
        for (int mi = 0; mi < 4; ++mi)
            #pragma unroll
            for (int r = 0; r < 4; ++r) {
                int mrow = mi * 16 + lg * 4 + r;
                float u = fmaf(xbuf[mrow], l1wn, l1bn);
                float s = fmaf(dn, u, acc[mi][nj][r]);
                h1[(row0 + mrow) * DIMD + n] = f2bf(fast_tanh(s) + u);
            }
    }
}

// ---- fused FFN v4: bf16 MFMA, M=64/block, 8 waves, FDIM chunks of 128 ----
// vs round 7 (184.8us, 2 barriers/chunk): fs is DOUBLE-BUFFERED so only ONE
// barrier per chunk: {phase1 (h1s LDS + enc L2, no fs hazard) -> write
// fs[c&1] -> barrier -> phase2 reads fs[c&1]}. Stale-reader hazard on
// fs[c&1] is phase2(c-2), separated by barrier(c-1). Waves drift a chunk
// apart -> phase1/phase2 of different waves overlap. 64 VGPR / 2 blocks/CU
// preserved (round-8 proved occupancy, not LDS conflicts, is binding).
__global__ __launch_bounds__(512, 4) void k_ff2(
        const ushort* __restrict__ h1g, const ushort* __restrict__ enc16,
        const float* __restrict__ enc_b, const ushort* __restrict__ dec16,
        const float* __restrict__ dec_b, const float* __restrict__ l2w,
        const float* __restrict__ l2b, float* __restrict__ out) {
    __shared__ ushort h1s[64 * 256];      // 32 KB, XOR-swizzled rows (512 B stride)
    __shared__ ushort fs[2][64 * 128];    // 2 x 16 KB, fsw-swizzled rows (256 B stride)
    __shared__ float osum[64];
    const int t = threadIdx.x;
    const int m0 = blockIdx.x * 64;
    const int w = t >> 6, l = t & 63;
    const int lr = l & 15, lg = l >> 4;

    #pragma unroll
    for (int e = 0; e < 4; ++e) {
        int flat = e * 512 + t;
        int row = flat >> 5, unit = flat & 31;
        s8bf v = *(const s8bf*)(h1g + (size_t)(m0 + row) * 256 + unit * 8);
        *(s8bf*)((char*)h1s + row * 512 + ((unit * 16) ^ ((row & 7) << 4))) = v;
    }
    if (t < 64) osum[t] = 0.f;
    __syncthreads();

    const f32x4 fz = {0.f, 0.f, 0.f, 0.f};
    f32x4 acc[4][2];
    #pragma unroll
    for (int mi = 0; mi < 4; ++mi) { acc[mi][0] = fz; acc[mi][1] = fz; }

    const ushort* encBase  = enc16 + (size_t)(w * 16 + lr) * 256;
    const ushort* decBase0 = dec16 + (size_t)(w * 32 + lr) * 2560;
    const ushort* decBase1 = dec16 + (size_t)(w * 32 + 16 + lr) * 2560;

    for (int c = 0; c < 20; ++c) {
        const int k0 = c * 128;
        char* fsC = (char*)fs[c & 1];
        // ---- phase 1: f chunk [64][128]; wave w owns f-col k0 + w*16 + lr ----
        f32x4 facc[4] = {fz, fz, fz, fz};
        const ushort* encRow = encBase + (size_t)k0 * 256;
        #pragma unroll
        for (int kd = 0; kd < 8; ++kd) {
            s8bf bfrag = *(const s8bf*)(encRow + kd * 32 + lg * 8);
            #pragma unroll
            for (int mi = 0; mi < 4; ++mi) {
                int row = mi * 16 + lr;
                int kb = kd * 64 + lg * 16;
                s8bf a = *(const s8bf*)((const char*)h1s + row * 512 + (kb ^ ((row & 7) << 4)));
                facc[mi] = MFMA16(a, bfrag, facc[mi]);
            }
        }
        float ebv = enc_b[k0 + w * 16 + lr];
        // ---- write fs[c&1] (stale readers done: phase2(c-2) < barrier(c-1)) ----
        #pragma unroll
        for (int mi = 0; mi < 4; ++mi)
            #pragma unroll
            for (int r = 0; r < 4; ++r) {
                int m = mi * 16 + 4 * lg + r;
                int kc = w * 16 + lr;
                *(ushort*)(fsC + m * 256 + ((kc * 2) ^ fsw(m))) =
                    f2bf(fast_tanh(facc[mi][r] + ebv));
            }
        __syncthreads();                      // fs[c&1] chunk ready for all waves
        // ---- phase 2: acc += f @ dec^T ; wave w owns h2-cols w*32+{0..31} ----
        #pragma unroll
        for (int kk = 0; kk < 4; ++kk) {
            s8bf b0 = *(const s8bf*)(decBase0 + k0 + kk * 32 + lg * 8);
            s8bf b1 = *(const s8bf*)(decBase1 + k0 + kk * 32 + lg * 8);
            #pragma unroll
            for (int mi = 0; mi < 4; ++mi) {
                int row = mi * 16 + lr;
                int kb = kk * 64 + lg * 16;
                s8bf a = *(const s8bf*)(fsC + row * 256 + (kb ^ fsw(row)));
                acc[mi][0] = MFMA16(a, b0, acc[mi][0]);
                acc[mi][1] = MFMA16(a, b1, acc[mi][1]);
            }
        }
    }
    // ---- epilogue: +dec_b + residual, dot l2w, reduce ----
    const int n0 = w * 32 + lr, n1 = n0 + 16;
    const float db0 = dec_b[n0], db1 = dec_b[n1];
    const float w0 = l2w[n0], w1 = l2w[n1];
    #pragma unroll
    for (int mi = 0; mi < 4; ++mi)
        #pragma unroll
        for (int r = 0; r < 4; ++r) {
            int m = mi * 16 + 4 * lg + r;
            float r0 = bf2f(*(const ushort*)((const char*)h1s + m * 512 + ((2 * n0) ^ ((m & 7) << 4))));
            float r1 = bf2f(*(const ushort*)((const char*)h1s + m * 512 + ((2 * n1) ^ ((m & 7) << 4))));
            float s = (acc[mi][0][r] + db0 + r0) * w0 + (acc[mi][1][r] + db1 + r1) * w1;
            s += __shfl_xor(s, 1, 16);
            s += __shfl_xor(s, 2, 16);
            s += __shfl_xor(s, 4, 16);
            s += __shfl_xor(s, 8, 16);
            if (lr == 0) atomicAdd(&osum[m], s);
        }
    __syncthreads();
    if (t < 64) out[m0 + t] = osum[t] + l2b[0];
}

extern "C" void kernel_launch(void* const* d_in, const int* in_sizes, int n_in,
                              void* d_out, int out_size, void* d_ws, size_t ws_size,
                              hipStream_t stream) {
    const float* x       = (const float*)d_in[0];
    const float* l1w     = (const float*)d_in[1];
    const float* l1b     = (const float*)d_in[2];
    const float* lam_re  = (const float*)d_in[3];
    const float* lam_im  = (const float*)d_in[4];
    const float* B_re    = (const float*)d_in[5];
    const float* B_im    = (const float*)d_in[6];
    const float* C_re    = (const float*)d_in[7];
    const float* C_im    = (const float*)d_in[8];
    const float* Dv      = (const float*)d_in[9];
    const float* log_stp = (const float*)d_in[10];
    const float* enc_w   = (const float*)d_in[11];
    const float* enc_b   = (const float*)d_in[12];
    const float* dec_w   = (const float*)d_in[13];
    const float* dec_b   = (const float*)d_in[14];
    const float* l2w     = (const float*)d_in[15];
    const float* l2b     = (const float*)d_in[16];
    float* ws  = (float*)d_ws;
    float* out = (float*)d_out;
    ushort* h1_16 = (ushort*)(ws + OFF_H1);
    ushort* enc16 = (ushort*)(ws + OFF_ENC16);
    ushort* dec16 = (ushort*)(ws + OFF_DEC16);
    ushort* cc16  = (ushort*)(ws + OFF_CC16);

    hipLaunchKernelGGL(k_prep, dim3(3073), dim3(256), 0, stream,
                       enc_w, dec_w, C_re, C_im, l1w, l1b, lam_re, lam_im,
                       B_re, B_im, log_stp, enc16, dec16, cc16, ws);
    hipLaunchKernelGGL(k_scanA, dim3(NCHUNK, NB), dim3(256), 0, stream, x, ws);
    hipLaunchKernelGGL(k_scanB, dim3(NB), dim3(256), 0, stream, ws);
    hipLaunchKernelGGL(k_scg, dim3(NCHUNK, NB), dim3(256), 0, stream,
                       x, ws, cc16, l1w, l1b, Dv, h1_16);
    hipLaunchKernelGGL(k_ff2, dim3(MTOT / 64), dim3(512), 0, stream,
                       h1_16, enc16, enc_b, dec16, dec_b, l2w, l2b, out);
}

// Round 10
// 232.664 us; speedup vs baseline: 1.4920x; 1.3296x over previous
//
#include <hip/hip_runtime.h>

#define DIMD 256
#define PDIM 256
#define NB   8
#define LSEQ 4096
#define MTOT (NB*LSEQ)      // 32768
#define FDIM 2560
#define NCHUNK 64
#define CLEN 64

typedef __attribute__((ext_vector_type(8))) short s8bf;   // 8 bf16 = 4 VGPRs
typedef __attribute__((ext_vector_type(4))) float f32x4;

#define MFMA16(a,b,c) __builtin_amdgcn_mfma_f32_16x16x32_bf16((a),(b),(c),0,0,0)

// ---- workspace layout (float offsets) ----
static const size_t OFF_LBR  = 0;      // lam_bar re           [256]
static const size_t OFF_LBI  = 256;    // lam_bar im
static const size_t OFF_A64R = 512;    // lam_bar^64 re
static const size_t OFF_A64I = 768;
static const size_t OFF_WR   = 1024;   // w = B_bar . l1_w
static const size_t OFF_WI   = 1280;
static const size_t OFF_CR   = 1536;   // c = B_bar . l1_b
static const size_t OFF_CI   = 1792;
static const size_t OFF_DBL2 = 2048;   // scalar: dec_b.l2w + l2b
static const size_t OFF_E_RE   = 4096;                       // chunk end states [8][64][256]
static const size_t OFF_E_IM   = OFF_E_RE   + 131072;
static const size_t OFF_CAR_RE = OFF_E_IM   + 131072;        // chunk carry-in   [8][64][256]
static const size_t OFF_CAR_IM = OFF_CAR_RE + 131072;
static const size_t OFF_H1     = OFF_CAR_IM + 131072;        // h1 bf16 [32768][256] (4,194,304 floats)
static const size_t OFF_ENC16  = OFF_H1     + 4194304;       // enc_w bf16 [2560][256]
static const size_t OFF_DL     = OFF_ENC16  + 327680;        // dl f32 [2560] = dec^T . l2w
static const size_t OFF_CC16   = OFF_DL     + 327680;        // Cc bf16 [256][512] k-interleaved
// end ~ 5.2M floats = 21 MB

__device__ __forceinline__ ushort f2bf(float f) {
    union { float f; unsigned u; } v; v.f = f;
    unsigned u = v.u;
    return (ushort)((u + 0x7FFFu + ((u >> 16) & 1u)) >> 16);   // RNE
}
__device__ __forceinline__ float bf2f(ushort h) {
    union { unsigned u; float f; } v; v.u = ((unsigned)h) << 16;
    return v.f;
}
// tanh = 1 - 2/(e^{2x}+1); rcp(inf)=0 -> +1, e^{2x}->0 -> -1: no clamps needed
__device__ __forceinline__ float fast_tanh(float x) {
    float e = __expf(2.f * x);
    return 1.f - 2.f * __builtin_amdgcn_rcpf(e + 1.f);
}

// ---- weight prep + consts + dl, one launch ----
// bid <2560: enc->bf16 ; 2560..3071: Cc16 ; 3072: per-p consts + (dec_b.l2w+l2b) ;
// 3073..3082: dl[k] = sum_n dec_w[n][k] * l2w[n]
__global__ void k_prep(const float* __restrict__ enc_w, const float* __restrict__ dec_w,
                       const float* __restrict__ C_re, const float* __restrict__ C_im,
                       const float* __restrict__ l1w, const float* __restrict__ l1b,
                       const float* __restrict__ lam_re, const float* __restrict__ lam_im,
                       const float* __restrict__ B_re, const float* __restrict__ B_im,
                       const float* __restrict__ log_step, const float* __restrict__ dec_b,
                       const float* __restrict__ l2w, const float* __restrict__ l2b,
                       ushort* __restrict__ enc16, ushort* __restrict__ cc16,
                       float* __restrict__ dlv, float* __restrict__ ws) {
    __shared__ float red[4];
    int bid = blockIdx.x, t = threadIdx.x;
    if (bid < 2560) {
        int i = bid * 256 + t;
        enc16[i] = f2bf(enc_w[i]);
    } else if (bid < 3072) {
        int j = (bid - 2560) * 256 + t;       // 512 blocks -> 131072 = 256*512
        int h = j >> 9, c = j & 511;
        int p = c >> 1;
        // Cc16[h][2p] = 2*C_re[h][p] ; Cc16[h][2p+1] = -2*C_im[h][p]  (matches xs)
        float v = ((c & 1) == 0) ? 2.f * C_re[h * 256 + p] : -2.f * C_im[h * 256 + p];
        cc16[j] = f2bf(v);
    } else if (bid == 3072) {
        int p = t;
        float st = expf(log_step[p]);
        float lr = lam_re[p], li = lam_im[p];
        float zr = lr * st, zi = li * st;
        float er = expf(zr);
        float lbr = er * cosf(zi), lbi = er * sinf(zi);
        float den = lr * lr + li * li;
        float nr = lbr - 1.0f, ni = lbi;
        float facr = (nr * lr + ni * li) / den;
        float faci = (ni * lr - nr * li) / den;
        float dwr = 0.f, dwi = 0.f, dbr = 0.f, dbi = 0.f;
        for (int h = 0; h < DIMD; ++h) {
            float br = B_re[p * DIMD + h], bi = B_im[p * DIMD + h];
            float w1 = l1w[h], b1 = l1b[h];
            dwr = fmaf(br, w1, dwr); dwi = fmaf(bi, w1, dwi);
            dbr = fmaf(br, b1, dbr); dbi = fmaf(bi, b1, dbi);
        }
        float wr = facr * dwr - faci * dwi, wi = facr * dwi + faci * dwr;
        float cr = facr * dbr - faci * dbi, ci = facr * dbi + faci * dbr;
        float ar = lbr, ai = lbi;
        for (int s = 0; s < 6; ++s) { float tq = ar * ar - ai * ai; ai = 2.f * ar * ai; ar = tq; }
        ws[OFF_LBR + p] = lbr;  ws[OFF_LBI + p] = lbi;
        ws[OFF_A64R + p] = ar;  ws[OFF_A64I + p] = ai;
        ws[OFF_WR + p] = wr;    ws[OFF_WI + p] = wi;
        ws[OFF_CR + p] = cr;    ws[OFF_CI + p] = ci;
        // scalar: dec_b . l2w + l2b
        float s = dec_b[t] * l2w[t];
        #pragma unroll
        for (int off = 1; off < 64; off <<= 1) s += __shfl_xor(s, off, 64);
        if ((t & 63) == 0) red[t >> 6] = s;
        __syncthreads();
        if (t == 0) ws[OFF_DBL2] = red[0] + red[1] + red[2] + red[3] + l2b[0];
    } else {
        int k = (bid - 3073) * 256 + t;       // 10 blocks -> 2560
        float s0 = 0.f, s1 = 0.f;
        for (int n = 0; n < 256; n += 2) {
            s0 = fmaf(dec_w[(size_t)n * FDIM + k], l2w[n], s0);
            s1 = fmaf(dec_w[(size_t)(n + 1) * FDIM + k], l2w[n + 1], s1);
        }
        dlv[k] = s0 + s1;
    }
}

// ---- scan pass A: per (b,chunk,p) chunk-local end state (zero init) ----
__global__ void k_scanA(const float* __restrict__ x, float* __restrict__ ws) {
    int p = threadIdx.x, chunk = blockIdx.x, b = blockIdx.y;
    float lbr = ws[OFF_LBR + p], lbi = ws[OFF_LBI + p];
    float wr = ws[OFF_WR + p], wi = ws[OFF_WI + p];
    float cr = ws[OFF_CR + p], ci = ws[OFF_CI + p];
    const float* xb = x + (size_t)b * LSEQ + chunk * CLEN;
    float sr = 0.f, si = 0.f;
    for (int t = 0; t < CLEN; ++t) {
        float xv = xb[t];
        float bur = fmaf(xv, wr, cr), bui = fmaf(xv, wi, ci);
        float nsr = fmaf(lbr, sr, fmaf(-lbi, si, bur));
        float nsi = fmaf(lbr, si, fmaf(lbi, sr, bui));
        sr = nsr; si = nsi;
    }
    size_t idx = ((size_t)b * NCHUNK + chunk) * PDIM + p;
    ws[OFF_E_RE + idx] = sr; ws[OFF_E_IM + idx] = si;
}

// ---- scan pass B: combine chunks, store carry-in per chunk ----
__global__ void k_scanB(float* __restrict__ ws) {
    int p = threadIdx.x, b = blockIdx.x;
    float ar = ws[OFF_A64R + p], ai = ws[OFF_A64I + p];
    float sr = 0.f, si = 0.f;
    for (int c = 0; c < NCHUNK; ++c) {
        size_t idx = ((size_t)b * NCHUNK + c) * PDIM + p;
        ws[OFF_CAR_RE + idx] = sr; ws[OFF_CAR_IM + idx] = si;
        float er = ws[OFF_E_RE + idx], ei = ws[OFF_E_IM + idx];
        float nsr = fmaf(ar, sr, fmaf(-ai, si, er));
        float nsi = fmaf(ar, si, fmaf(ai, sr, ei));
        sr = nsr; si = nsi;
    }
}

// ---- fused scanC + C-projection (bf16 MFMA) + S5 epilogue -> h1 bf16 ----
__global__ __launch_bounds__(256) void k_scg(
        const float* __restrict__ x, const float* __restrict__ ws,
        const ushort* __restrict__ cc16, const float* __restrict__ l1w,
        const float* __restrict__ l1b, const float* __restrict__ Dv,
        ushort* __restrict__ h1) {
    __shared__ ushort xs[64 * 512];   // 64 KB: row=t (1024B), col 2p=re, 2p+1=im
    __shared__ float xbuf[64];
    const int t = threadIdx.x;
    const int chunk = blockIdx.x, b = blockIdx.y;
    const size_t row0 = (size_t)b * LSEQ + chunk * CLEN;
    if (t < 64) xbuf[t] = x[row0 + t];
    const int p = t;
    float lbr = ws[OFF_LBR + p], lbi = ws[OFF_LBI + p];
    float wr = ws[OFF_WR + p], wi = ws[OFF_WI + p];
    float cr = ws[OFF_CR + p], ci = ws[OFF_CI + p];
    size_t cidx = ((size_t)b * NCHUNK + chunk) * PDIM + p;
    float sr = ws[OFF_CAR_RE + cidx], si = ws[OFF_CAR_IM + cidx];
    __syncthreads();
    for (int tt = 0; tt < CLEN; ++tt) {
        float xv = xbuf[tt];
        float bur = fmaf(xv, wr, cr), bui = fmaf(xv, wi, ci);
        float nsr = fmaf(lbr, sr, fmaf(-lbi, si, bur));
        float nsi = fmaf(lbr, si, fmaf(lbi, sr, bui));
        sr = nsr; si = nsi;
        unsigned pk;
        asm("v_cvt_pk_bf16_f32 %0, %1, %2" : "=v"(pk) : "v"(sr), "v"(si));
        *(unsigned*)((char*)xs + tt * 1024 + ((p * 4) ^ ((tt & 7) << 4))) = pk;
    }
    __syncthreads();
    // GEMM: out 64x256, K=512
    const int w = t >> 6, l = t & 63, lr = l & 15, lg = l >> 4;
    const f32x4 fz = {0.f, 0.f, 0.f, 0.f};
    f32x4 acc[4][4];
    #pragma unroll
    for (int mi = 0; mi < 4; ++mi)
        #pragma unroll
        for (int nj = 0; nj < 4; ++nj) acc[mi][nj] = fz;
    for (int ks = 0; ks < 16; ++ks) {
        s8bf a[4];
        #pragma unroll
        for (int mi = 0; mi < 4; ++mi) {
            int row = mi * 16 + lr;
            a[mi] = *(const s8bf*)((const char*)xs + row * 1024 + ((ks * 64 + lg * 16) ^ ((row & 7) << 4)));
        }
        #pragma unroll
        for (int nj = 0; nj < 4; ++nj) {
            int n = w * 64 + nj * 16 + lr;
            s8bf bfrag = *(const s8bf*)(cc16 + (size_t)n * 512 + ks * 32 + lg * 8);
            #pragma unroll
            for (int mi = 0; mi < 4; ++mi)
                acc[mi][nj] = MFMA16(a[mi], bfrag, acc[mi][nj]);
        }
    }
    // epilogue: u = x*l1w + l1b ; h1 = tanh(D*u + 2Re(Cx)) + u   (2x folded into Cc16)
    #pragma unroll
    for (int nj = 0; nj < 4; ++nj) {
        int n = w * 64 + nj * 16 + lr;
        float l1wn = l1w[n], l1bn = l1b[n], dn = Dv[n];
        #pragma unroll
        for (int mi = 0; mi < 4; ++mi)
            #pragma unroll
            for (int r = 0; r < 4; ++r) {
                int mrow = mi * 16 + lg * 4 + r;
                float u = fmaf(xbuf[mrow], l1wn, l1bn);
                float s = fmaf(dn, u, acc[mi][nj][r]);
                h1[(row0 + mrow) * DIMD + n] = f2bf(fast_tanh(s) + u);
            }
    }
}

// ---- FFN v5 (k_ff3): dec-GEMM folded into dl = dec^T.l2w ----
// out[m] = sum_k tanh(h1 enc^T + eb)[m][k]*dl[k] + sum_n h1[m][n]*l2w[n] + (dec_b.l2w + l2b)
// Loop body: 8 enc L2 loads + 32 MFMA (A hoisted in registers) + 16 tanh + 16 FMA.
// NO LDS ops, NO barriers in the loop -- waves free-run (r8/r9 falsified LDS-BW
// and barrier-count theories; serialization was the cost, so remove it).
__global__ __launch_bounds__(512, 2) void k_ff3(
        const ushort* __restrict__ h1g, const ushort* __restrict__ enc16,
        const float* __restrict__ enc_b, const float* __restrict__ dlv,
        const float* __restrict__ l2w, const float* __restrict__ wsc,
        float* __restrict__ out) {
    __shared__ ushort h1s[64 * 256];   // 32 KB, XOR-swizzled rows (512 B stride)
    __shared__ float osum[64];
    const int t = threadIdx.x;
    const int m0 = blockIdx.x * 64;
    const int w = t >> 6, l = t & 63;
    const int lr = l & 15, lg = l >> 4;

    #pragma unroll
    for (int e = 0; e < 4; ++e) {
        int flat = e * 512 + t;
        int row = flat >> 5, unit = flat & 31;
        s8bf v = *(const s8bf*)(h1g + (size_t)(m0 + row) * 256 + unit * 8);
        *(s8bf*)((char*)h1s + row * 512 + ((unit * 16) ^ ((row & 7) << 4))) = v;
    }
    __syncthreads();

    // ---- osum[m] init: residual dot  sum_n h1[m][n]*l2w[n]  + (dec_b.l2w+l2b) ----
    {
        const int m = t >> 3, j = t & 7;       // 8 threads per row
        float rs = 0.f;
        #pragma unroll
        for (int q = 0; q < 4; ++q) {
            int n = j * 32 + q * 8;
            s8bf v = *(const s8bf*)((const char*)h1s + m * 512 + ((2 * n) ^ ((m & 7) << 4)));
            #pragma unroll
            for (int e = 0; e < 8; ++e)
                rs = fmaf(bf2f((ushort)v[e]), l2w[n + e], rs);
        }
        rs += __shfl_xor(rs, 1, 8);
        rs += __shfl_xor(rs, 2, 8);
        rs += __shfl_xor(rs, 4, 8);
        if (j == 0) osum[m] = rs + wsc[OFF_DBL2];
    }

    // ---- one-time: A-fragments from h1s into registers (chunk-invariant) ----
    s8bf aReg[4][8];
    #pragma unroll
    for (int mi = 0; mi < 4; ++mi) {
        int row = mi * 16 + lr;
        #pragma unroll
        for (int kd = 0; kd < 8; ++kd) {
            int kb = kd * 64 + lg * 16;
            aReg[mi][kd] = *(const s8bf*)((const char*)h1s + row * 512 + (kb ^ ((row & 7) << 4)));
        }
    }
    __syncthreads();    // osum inits visible before any atomicAdd below

    const f32x4 fz = {0.f, 0.f, 0.f, 0.f};
    float dacc[4][4] = {{0.f}};
    const ushort* encBase = enc16 + (size_t)(w * 16 + lr) * 256;

    for (int c = 0; c < 20; ++c) {
        const int k0 = c * 128;
        const int kc = k0 + w * 16 + lr;       // this lane's f-column
        f32x4 facc[4] = {fz, fz, fz, fz};
        const ushort* encRow = encBase + (size_t)k0 * 256;
        #pragma unroll
        for (int kd = 0; kd < 8; ++kd) {
            s8bf bfrag = *(const s8bf*)(encRow + kd * 32 + lg * 8);
            #pragma unroll
            for (int mi = 0; mi < 4; ++mi)
                facc[mi] = MFMA16(aReg[mi][kd], bfrag, facc[mi]);
        }
        float ebv = enc_b[kc];
        float dlk = dlv[kc];
        #pragma unroll
        for (int mi = 0; mi < 4; ++mi)
            #pragma unroll
            for (int r = 0; r < 4; ++r)
                dacc[mi][r] = fmaf(fast_tanh(facc[mi][r] + ebv), dlk, dacc[mi][r]);
    }
    // ---- reduce dacc over the 16 lr-lanes (same m), atomic into osum ----
    #pragma unroll
    for (int mi = 0; mi < 4; ++mi)
        #pragma unroll
        for (int r = 0; r < 4; ++r) {
            float s = dacc[mi][r];
            s += __shfl_xor(s, 1, 16);
            s += __shfl_xor(s, 2, 16);
            s += __shfl_xor(s, 4, 16);
            s += __shfl_xor(s, 8, 16);
            if (lr == 0) atomicAdd(&osum[mi * 16 + 4 * lg + r], s);
        }
    __syncthreads();
    if (t < 64) out[m0 + t] = osum[t];
}

extern "C" void kernel_launch(void* const* d_in, const int* in_sizes, int n_in,
                              void* d_out, int out_size, void* d_ws, size_t ws_size,
                              hipStream_t stream) {
    const float* x       = (const float*)d_in[0];
    const float* l1w     = (const float*)d_in[1];
    const float* l1b     = (const float*)d_in[2];
    const float* lam_re  = (const float*)d_in[3];
    const float* lam_im  = (const float*)d_in[4];
    const float* B_re    = (const float*)d_in[5];
    const float* B_im    = (const float*)d_in[6];
    const float* C_re    = (const float*)d_in[7];
    const float* C_im    = (const float*)d_in[8];
    const float* Dv      = (const float*)d_in[9];
    const float* log_stp = (const float*)d_in[10];
    const float* enc_w   = (const float*)d_in[11];
    const float* enc_b   = (const float*)d_in[12];
    const float* dec_w   = (const float*)d_in[13];
    const float* dec_b   = (const float*)d_in[14];
    const float* l2w     = (const float*)d_in[15];
    const float* l2b     = (const float*)d_in[16];
    float* ws  = (float*)d_ws;
    float* out = (float*)d_out;
    ushort* h1_16 = (ushort*)(ws + OFF_H1);
    ushort* enc16 = (ushort*)(ws + OFF_ENC16);
    float*  dlv   = ws + OFF_DL;
    ushort* cc16  = (ushort*)(ws + OFF_CC16);

    hipLaunchKernelGGL(k_prep, dim3(3083), dim3(256), 0, stream,
                       enc_w, dec_w, C_re, C_im, l1w, l1b, lam_re, lam_im,
                       B_re, B_im, log_stp, dec_b, l2w, l2b,
                       enc16, cc16, dlv, ws);
    hipLaunchKernelGGL(k_scanA, dim3(NCHUNK, NB), dim3(256), 0, stream, x, ws);
    hipLaunchKernelGGL(k_scanB, dim3(NB), dim3(256), 0, stream, ws);
    hipLaunchKernelGGL(k_scg, dim3(NCHUNK, NB), dim3(256), 0, stream,
                       x, ws, cc16, l1w, l1b, Dv, h1_16);
    hipLaunchKernelGGL(k_ff3, dim3(MTOT / 64), dim3(512), 0, stream,
                       h1_16, enc16, enc_b, dlv, l2w, ws, out);
}